// Round 4
// baseline (513.936 us; speedup 1.0000x reference)
//
#include <hip/hip_runtime.h>
#include <hip/hip_bf16.h>

// CrossAttention R3b (R3 + compile fix: manual bf16 pair packing, no bit_cast of
// __hip_bfloat162). vs R2 (510us; attn 246us, MfmaUtil 11%, VALU 19.7% -> latency-bound,
// VGPR=84 proves compiler serialized K/V loads into the dependency chain):
//  - attn: single-wave blocks, explicit K/V register double-buffer prefetched one full
//    tile ahead (__launch_bounds__(64,2) so ~220 VGPR can stay live, 2 waves/SIMD),
//    per-mt fused softmax (short st liveness), packed bf16 cvt.
//  - GEMMs unchanged from R2.

typedef short bf16x8 __attribute__((ext_vector_type(8)));
typedef float f32x4 __attribute__((ext_vector_type(4)));

__device__ __forceinline__ short f2s(float f) {
    __hip_bfloat16 h = __float2bfloat16(f);
    return __builtin_bit_cast(short, h);
}

__device__ __forceinline__ unsigned int pack2(float a, float b) {
    unsigned int lo = (unsigned short)f2s(a);
    unsigned int hi = (unsigned short)f2s(b);
    return lo | (hi << 16);
}

__device__ __forceinline__ f32x4 mfma16(bf16x8 a, bf16x8 b, f32x4 c) {
    return __builtin_amdgcn_mfma_f32_16x16x32_bf16(a, b, c, 0, 0, 0);
}

__device__ __forceinline__ void gload16(short* lds, const short* g) {
    __builtin_amdgcn_global_load_lds((const __attribute__((address_space(1))) void*)g,
                                     (__attribute__((address_space(3))) void*)lds,
                                     16, 0, 0);
}

// ---------------- prep: fp32 -> bf16 for activations ----------------
__global__ __launch_bounds__(256) void conv_to_bf16(const float* __restrict__ x,
                                                    const float* __restrict__ ctx,
                                                    short* __restrict__ xb,
                                                    short* __restrict__ cb) {
    const size_t NV = 2097152;
    size_t i = (size_t)blockIdx.x * 256 + threadIdx.x;
    const float4* src = (i < NV) ? (const float4*)x : (const float4*)ctx;
    short* dst = (i < NV) ? xb : cb;
    size_t idx = (i < NV) ? i : i - NV;
    float4 v = src[idx];
    short4 o;
    o.x = f2s(v.x); o.y = f2s(v.y); o.z = f2s(v.z); o.w = f2s(v.w);
    ((short4*)dst)[idx] = o;
}

// ---------------- prep: W -> W^T bf16 ----------------
__global__ __launch_bounds__(256) void transpose_weights(
    const float* __restrict__ q_w, const float* __restrict__ kv_w,
    const float* __restrict__ proj_w,
    short* __restrict__ WqT, short* __restrict__ WkT,
    short* __restrict__ WvT, short* __restrict__ WpT) {
    __shared__ float t[32][33];
    const float* src; short* dst; int ld, coff;
    switch (blockIdx.z) {
        case 0:  src = q_w;    dst = WqT; ld = 1024; coff = 0;    break;
        case 1:  src = kv_w;   dst = WkT; ld = 2048; coff = 0;    break;
        case 2:  src = kv_w;   dst = WvT; ld = 2048; coff = 1024; break;
        default: src = proj_w; dst = WpT; ld = 1024; coff = 0;    break;
    }
    int n0 = blockIdx.x * 32, k0 = blockIdx.y * 32;
    int tx = threadIdx.x & 31, ty = threadIdx.x >> 5;
    #pragma unroll
    for (int j = 0; j < 32; j += 8)
        t[ty + j][tx] = src[(size_t)(k0 + ty + j) * ld + coff + n0 + tx];
    __syncthreads();
    #pragma unroll
    for (int j = 0; j < 32; j += 8)
        dst[(size_t)(n0 + ty + j) * 1024 + k0 + tx] = f2s(t[tx][ty + j]);
}

// ---------------- GEMM 128x128 tile (unchanged from R2) ----------------
template <int MODE>
__global__ __launch_bounds__(256) void gemm128(
    const short* __restrict__ A,
    const short* __restrict__ Bt,
    const float* __restrict__ ln_scale,
    const float* __restrict__ ln_bias,
    short* __restrict__ outB,
    float* __restrict__ outF,
    const float* __restrict__ bias_vec) {
    __shared__ short smem[(MODE <= 1) ? 128 * 132 : 128 * 64];
    short* Asm = smem;
    short* Bsm = smem + 128 * 32;

    const int tid = threadIdx.x;
    const int w = tid >> 6, lane = tid & 63, quad = lane >> 4, l15 = lane & 15;
    const int wr = w & 1, wc = w >> 1;
    const int m0 = blockIdx.y * 128, n0 = blockIdx.x * 128;

    const int srow = lane >> 2, slot = lane & 3;
    const int kslot = (slot ^ ((srow >> 1) & 3)) * 8;
    const short* Ag0 = A + (size_t)(m0 + w * 32 + srow) * 1024 + kslot;
    const short* Ag1 = Ag0 + (size_t)16 * 1024;
    const short* Bg0 = Bt + (size_t)(n0 + w * 32 + srow) * 1024 + kslot;
    const short* Bg1 = Bg0 + (size_t)16 * 1024;
    short* Al = Asm + w * 32 * 32;
    short* Bl = Bsm + w * 32 * 32;

    f32x4 acc[4][4];
    #pragma unroll
    for (int r = 0; r < 4; r++)
        #pragma unroll
        for (int c = 0; c < 4; c++) acc[r][c] = f32x4{0.f, 0.f, 0.f, 0.f};

    const int rsw = (l15 >> 1) & 3;
    for (int k0 = 0; k0 < 1024; k0 += 32) {
        __syncthreads();
        gload16(Al,           Ag0 + k0);
        gload16(Al + 16 * 32, Ag1 + k0);
        gload16(Bl,           Bg0 + k0);
        gload16(Bl + 16 * 32, Bg1 + k0);
        __syncthreads();
        bf16x8 af[4], bfr[4];
        #pragma unroll
        for (int rt = 0; rt < 4; rt++)
            af[rt] = *(const bf16x8*)(Asm + (wr * 64 + rt * 16 + l15) * 32 + ((quad ^ rsw) * 8));
        #pragma unroll
        for (int ct = 0; ct < 4; ct++)
            bfr[ct] = *(const bf16x8*)(Bsm + (wc * 64 + ct * 16 + l15) * 32 + ((quad ^ rsw) * 8));
        #pragma unroll
        for (int rt = 0; rt < 4; rt++)
            #pragma unroll
            for (int ct = 0; ct < 4; ct++)
                acc[rt][ct] = mfma16(af[rt], bfr[ct], acc[rt][ct]);
    }

    if constexpr (MODE == 0 || MODE == 1) {
        #pragma unroll
        for (int rt = 0; rt < 4; rt++) {
            #pragma unroll
            for (int i = 0; i < 4; i++) {
                float s = acc[rt][0][i] + acc[rt][1][i] + acc[rt][2][i] + acc[rt][3][i];
                float q = acc[rt][0][i] * acc[rt][0][i] + acc[rt][1][i] * acc[rt][1][i] +
                          acc[rt][2][i] * acc[rt][2][i] + acc[rt][3][i] * acc[rt][3][i];
                #pragma unroll
                for (int off = 1; off < 16; off <<= 1) {
                    s += __shfl_xor(s, off, 64);
                    q += __shfl_xor(q, off, 64);
                }
                float mu = s * (1.f / 64.f);
                float var = q * (1.f / 64.f) - mu * mu;
                float rs = rsqrtf(var + 1e-5f);
                float vals[4];
                #pragma unroll
                for (int ct = 0; ct < 4; ct++) {
                    int hd = ct * 16 + l15;
                    vals[ct] = (acc[rt][ct][i] - mu) * rs * ln_scale[hd] + ln_bias[hd];
                }
                if constexpr (MODE == 0) {
                    int sp = (m0 + wr * 64 + rt * 16 + quad * 4 + i) & 2047;
                    #pragma unroll
                    for (int ct = 0; ct < 2; ct++) {
                        int hd1 = ct * 16 + l15;
                        float ang = (float)sp * exp2f((float)hd1 * (-13.287712379549449f / 32.f));
                        float sn, cs;
                        sincosf(ang, &sn, &cs);
                        float v1 = vals[ct], v2 = vals[ct + 2];
                        vals[ct]     = v1 * cs - v2 * sn;
                        vals[ct + 2] = v1 * sn + v2 * cs;
                    }
                }
                #pragma unroll
                for (int ct = 0; ct < 4; ct++) acc[rt][ct][i] = vals[ct];
            }
        }
        __syncthreads();
        short* Csm = smem;
        #pragma unroll
        for (int rt = 0; rt < 4; rt++)
            #pragma unroll
            for (int ct = 0; ct < 4; ct++)
                #pragma unroll
                for (int i = 0; i < 4; i++)
                    Csm[(wr * 64 + rt * 16 + quad * 4 + i) * 132 + wc * 64 + ct * 16 + l15] =
                        f2s(acc[rt][ct][i]);
        __syncthreads();
        #pragma unroll
        for (int it = 0; it < 8; it++) {
            int row = it * 16 + (tid >> 4);
            int chunk = tid & 15;
            bf16x8 v = *(const bf16x8*)(Csm + row * 132 + chunk * 8);
            int hh = (n0 >> 6) + (chunk >> 3);
            int m = m0 + row, b = m >> 11, sp = m & 2047;
            *(bf16x8*)(outB + ((size_t)(b * 16 + hh) * 2048 + sp) * 64 + (chunk & 7) * 8) = v;
        }
    } else if constexpr (MODE == 2) {
        const int b = m0 >> 11, h = (n0 >> 6) + wc;
        const int sp = (m0 & 2047) + wr * 64 + quad * 4;
        #pragma unroll
        for (int rt = 0; rt < 4; rt++)
            #pragma unroll
            for (int ct = 0; ct < 4; ct++) {
                short4 pk;
                pk.x = f2s(acc[rt][ct][0]); pk.y = f2s(acc[rt][ct][1]);
                pk.z = f2s(acc[rt][ct][2]); pk.w = f2s(acc[rt][ct][3]);
                int hd = ct * 16 + l15;
                *(short4*)(outB + ((size_t)(b * 16 + h) * 64 + hd) * 2048 + sp + rt * 16) = pk;
            }
    } else {
        #pragma unroll
        for (int rt = 0; rt < 4; rt++)
            #pragma unroll
            for (int i = 0; i < 4; i++) {
                size_t m = m0 + wr * 64 + rt * 16 + quad * 4 + i;
                #pragma unroll
                for (int ct = 0; ct < 4; ct++) {
                    int n = n0 + wc * 64 + ct * 16 + l15;
                    outF[m * 1024 + n] = acc[rt][ct][i] + bias_vec[n];
                }
            }
    }
}

// ---------------- attention R3: single-wave blocks, register-double-buffered K/V ----------------
// S^T = K.Q^T; fixed-max softmax p = exp2(s*0.125*log2e - 8*log2e) (|s|<=8 by LN);
// deferred denominator. K(t+1)/V(t+1) prefetched a full tile ahead into registers.
__global__ __launch_bounds__(64, 2) void attn_kernel(
    const short* __restrict__ Q,   // [64][2048][64]
    const short* __restrict__ K,   // [64][2048][64]
    const short* __restrict__ V,   // [64][64][2048]  (V^T)
    short* __restrict__ AO) {      // [8192][1024] bf16
    __shared__ short Psm[32 * 72];  // P^T[qrow(32)][kcol(64)], stride 72
    const int lane = threadIdx.x;
    const int quad = lane >> 4, l15 = lane & 15;
    const int qt = blockIdx.x, bh = blockIdx.y;
    const short* Qb = Q + (size_t)bh * 2048 * 64;
    const short* Kb = K + (size_t)bh * 2048 * 64;
    const short* Vb = V + (size_t)bh * 64 * 2048;
    const int q0 = qt * 32;

    bf16x8 bq[2][2];  // Q as B-operand: B[n=qrow][k=hd] — resident all kernel
    #pragma unroll
    for (int nt = 0; nt < 2; nt++)
        #pragma unroll
        for (int ks = 0; ks < 2; ks++)
            bq[nt][ks] = *(const bf16x8*)(Qb + (size_t)(q0 + nt * 16 + l15) * 64 + ks * 32 + quad * 8);

    f32x4 acco[4][2];  // O^T: [ct(hd)][nt(qrow)]
    #pragma unroll
    for (int ct = 0; ct < 4; ct++)
        #pragma unroll
        for (int nt = 0; nt < 2; nt++) acco[ct][nt] = f32x4{0.f, 0.f, 0.f, 0.f};
    float lsum[2] = {0.f, 0.f};

    auto loadK = [&](bf16x8 (&d)[4][2], int sc) {
        #pragma unroll
        for (int mt = 0; mt < 4; mt++)
            #pragma unroll
            for (int ks = 0; ks < 2; ks++)
                d[mt][ks] = *(const bf16x8*)(Kb + (size_t)(sc + mt * 16 + l15) * 64 + ks * 32 + quad * 8);
    };
    auto loadV = [&](bf16x8 (&d)[4][2], int sc) {
        #pragma unroll
        for (int ct = 0; ct < 4; ct++)
            #pragma unroll
            for (int ks = 0; ks < 2; ks++)
                d[ct][ks] = *(const bf16x8*)(Vb + (size_t)(ct * 16 + l15) * 2048 + sc + ks * 32 + quad * 8);
    };
    auto tile = [&](bf16x8 (&ak)[4][2], bf16x8 (&av)[4][2]) {
        // QK^T + softmax, fused per-mt to keep st liveness short
        #pragma unroll
        for (int mt = 0; mt < 4; mt++) {
            #pragma unroll
            for (int nt = 0; nt < 2; nt++) {
                f32x4 st = f32x4{0.f, 0.f, 0.f, 0.f};
                st = mfma16(ak[mt][0], bq[nt][0], st);
                st = mfma16(ak[mt][1], bq[nt][1], st);
                float p0 = __builtin_amdgcn_exp2f(st[0] * 0.1803368801f - 11.5415605f);
                float p1 = __builtin_amdgcn_exp2f(st[1] * 0.1803368801f - 11.5415605f);
                float p2 = __builtin_amdgcn_exp2f(st[2] * 0.1803368801f - 11.5415605f);
                float p3 = __builtin_amdgcn_exp2f(st[3] * 0.1803368801f - 11.5415605f);
                lsum[nt] += (p0 + p1) + (p2 + p3);
                uint2 pw;
                pw.x = pack2(p0, p1);
                pw.y = pack2(p2, p3);
                *(uint2*)(Psm + (nt * 16 + l15) * 72 + mt * 16 + quad * 4) = pw;
            }
        }
        // P^T readback as B-operand (wave-private LDS, compiler orders lgkmcnt)
        bf16x8 bp[2][2];
        #pragma unroll
        for (int nt = 0; nt < 2; nt++)
            #pragma unroll
            for (int ks = 0; ks < 2; ks++)
                bp[nt][ks] = *(const bf16x8*)(Psm + (nt * 16 + l15) * 72 + ks * 32 + quad * 8);
        #pragma unroll
        for (int ct = 0; ct < 4; ct++)
            #pragma unroll
            for (int nt = 0; nt < 2; nt++)
                #pragma unroll
                for (int ks = 0; ks < 2; ks++)
                    acco[ct][nt] = mfma16(av[ct][ks], bp[nt][ks], acco[ct][nt]);
    };

    bf16x8 ak0[4][2], ak1[4][2], av0[4][2], av1[4][2];
    loadK(ak0, 0);
    loadV(av0, 0);
    #pragma unroll 1
    for (int sc0 = 0; sc0 < 2048; sc0 += 128) {
        // prefetch next tile a full tile-compute ahead (final iter reads the tail of
        // K/V buffers' 16MB regions inside d_ws: safe, values unused)
        loadK(ak1, sc0 + 64);
        loadV(av1, sc0 + 64);
        tile(ak0, av0);
        if (sc0 + 128 < 2048) {
            loadK(ak0, sc0 + 128);
            loadV(av0, sc0 + 128);
        }
        tile(ak1, av1);
    }

    #pragma unroll
    for (int nt = 0; nt < 2; nt++) {
        lsum[nt] += __shfl_xor(lsum[nt], 16, 64);
        lsum[nt] += __shfl_xor(lsum[nt], 32, 64);
    }
    const int b = bh >> 4, h = bh & 15;
    #pragma unroll
    for (int nt = 0; nt < 2; nt++) {
        float inv = 1.f / lsum[nt];
        int sq = q0 + nt * 16 + l15;
        #pragma unroll
        for (int ct = 0; ct < 4; ct++) {
            short4 pk;
            pk.x = f2s(acco[ct][nt][0] * inv); pk.y = f2s(acco[ct][nt][1] * inv);
            pk.z = f2s(acco[ct][nt][2] * inv); pk.w = f2s(acco[ct][nt][3] * inv);
            *(short4*)(AO + ((size_t)b * 2048 + sq) * 1024 + h * 64 + ct * 16 + quad * 4) = pk;
        }
    }
}

extern "C" void kernel_launch(void* const* d_in, const int* in_sizes, int n_in,
                              void* d_out, int out_size, void* d_ws, size_t ws_size,
                              hipStream_t stream) {
    (void)in_sizes; (void)n_in; (void)out_size; (void)ws_size;
    const float* x      = (const float*)d_in[0];
    const float* ctx    = (const float*)d_in[1];
    const float* q_w    = (const float*)d_in[2];
    const float* kv_w   = (const float*)d_in[3];
    const float* qn_s   = (const float*)d_in[4];
    const float* qn_b   = (const float*)d_in[5];
    const float* kn_s   = (const float*)d_in[6];
    const float* kn_b   = (const float*)d_in[7];
    const float* proj_w = (const float*)d_in[8];
    const float* proj_b = (const float*)d_in[9];
    float* out = (float*)d_out;

    char* ws = (char*)d_ws;
    const size_t MB = 1024 * 1024;
    short* xb  = (short*)(ws + 0 * MB);
    short* cb  = (short*)(ws + 16 * MB);
    short* Qb  = (short*)(ws + 32 * MB);   // [64][2048][64] post LN+RoPE
    short* Kb  = (short*)(ws + 48 * MB);   // [64][2048][64] post LN
    short* Vt  = (short*)(ws + 64 * MB);   // [64][64][2048]
    short* AO  = (short*)(ws + 80 * MB);   // [8192][1024]
    short* WqT = (short*)(ws + 96 * MB);
    short* WkT = (short*)(ws + 98 * MB);
    short* WvT = (short*)(ws + 100 * MB);
    short* WpT = (short*)(ws + 102 * MB);

    conv_to_bf16<<<16384, 256, 0, stream>>>(x, ctx, xb, cb);
    transpose_weights<<<dim3(32, 32, 4), 256, 0, stream>>>(q_w, kv_w, proj_w, WqT, WkT, WvT, WpT);
    gemm128<0><<<dim3(8, 64), 256, 0, stream>>>(xb, WqT, qn_s, qn_b, Qb, nullptr, nullptr);
    gemm128<1><<<dim3(8, 64), 256, 0, stream>>>(cb, WkT, kn_s, kn_b, Kb, nullptr, nullptr);
    gemm128<2><<<dim3(8, 64), 256, 0, stream>>>(cb, WvT, nullptr, nullptr, Vt, nullptr, nullptr);
    attn_kernel<<<dim3(64, 64), 64, 0, stream>>>(Qb, Kb, Vt, AO);
    gemm128<3><<<dim3(8, 64), 256, 0, stream>>>(AO, WpT, nullptr, nullptr, nullptr, out, proj_b);
}

// Round 5
// 377.173 us; speedup vs baseline: 1.3626x; 1.3626x over previous
//
#include <hip/hip_runtime.h>
#include <hip/hip_bf16.h>

// CrossAttention R4. vs R3b (514us; attn 249us, MfmaUtil 11%, VALU 19% — register-sourced
// K/V designs latency-stall ~70% regardless of prefetch):
//  - attn rebuilt in the m97 GEMM shape: 4-wave blocks, K/V staged to LDS once per block
//    via global_load_lds w=16 + XOR swizzle, double-buffered, 1 barrier/tile.
//  - softmax: v_perm truncation packing (1 inst / 2 values), denominator sums truncated
//    values (exact softmax, no bias).
//  - grid (bh, qt): all q-blocks of a head on one XCD -> K/V streams L2 once.

typedef short bf16x8 __attribute__((ext_vector_type(8)));
typedef float f32x4 __attribute__((ext_vector_type(4)));

__device__ __forceinline__ short f2s(float f) {
    __hip_bfloat16 h = __float2bfloat16(f);
    return __builtin_bit_cast(short, h);
}

__device__ __forceinline__ f32x4 mfma16(bf16x8 a, bf16x8 b, f32x4 c) {
    return __builtin_amdgcn_mfma_f32_16x16x32_bf16(a, b, c, 0, 0, 0);
}

__device__ __forceinline__ void gload16(short* lds, const short* g) {
    __builtin_amdgcn_global_load_lds((const __attribute__((address_space(1))) void*)g,
                                     (__attribute__((address_space(3))) void*)lds,
                                     16, 0, 0);
}

__device__ __forceinline__ unsigned int fbits(float f) {
    return __builtin_bit_cast(unsigned int, f);
}
__device__ __forceinline__ float bitsf(unsigned int u) {
    return __builtin_bit_cast(float, u);
}

// ---------------- prep: fp32 -> bf16 for activations ----------------
__global__ __launch_bounds__(256) void conv_to_bf16(const float* __restrict__ x,
                                                    const float* __restrict__ ctx,
                                                    short* __restrict__ xb,
                                                    short* __restrict__ cb) {
    const size_t NV = 2097152;
    size_t i = (size_t)blockIdx.x * 256 + threadIdx.x;
    const float4* src = (i < NV) ? (const float4*)x : (const float4*)ctx;
    short* dst = (i < NV) ? xb : cb;
    size_t idx = (i < NV) ? i : i - NV;
    float4 v = src[idx];
    short4 o;
    o.x = f2s(v.x); o.y = f2s(v.y); o.z = f2s(v.z); o.w = f2s(v.w);
    ((short4*)dst)[idx] = o;
}

// ---------------- prep: W -> W^T bf16 ----------------
__global__ __launch_bounds__(256) void transpose_weights(
    const float* __restrict__ q_w, const float* __restrict__ kv_w,
    const float* __restrict__ proj_w,
    short* __restrict__ WqT, short* __restrict__ WkT,
    short* __restrict__ WvT, short* __restrict__ WpT) {
    __shared__ float t[32][33];
    const float* src; short* dst; int ld, coff;
    switch (blockIdx.z) {
        case 0:  src = q_w;    dst = WqT; ld = 1024; coff = 0;    break;
        case 1:  src = kv_w;   dst = WkT; ld = 2048; coff = 0;    break;
        case 2:  src = kv_w;   dst = WvT; ld = 2048; coff = 1024; break;
        default: src = proj_w; dst = WpT; ld = 1024; coff = 0;    break;
    }
    int n0 = blockIdx.x * 32, k0 = blockIdx.y * 32;
    int tx = threadIdx.x & 31, ty = threadIdx.x >> 5;
    #pragma unroll
    for (int j = 0; j < 32; j += 8)
        t[ty + j][tx] = src[(size_t)(k0 + ty + j) * ld + coff + n0 + tx];
    __syncthreads();
    #pragma unroll
    for (int j = 0; j < 32; j += 8)
        dst[(size_t)(n0 + ty + j) * 1024 + k0 + tx] = f2s(t[tx][ty + j]);
}

// ---------------- GEMM 128x128 tile (unchanged from R2) ----------------
template <int MODE>
__global__ __launch_bounds__(256) void gemm128(
    const short* __restrict__ A,
    const short* __restrict__ Bt,
    const float* __restrict__ ln_scale,
    const float* __restrict__ ln_bias,
    short* __restrict__ outB,
    float* __restrict__ outF,
    const float* __restrict__ bias_vec) {
    __shared__ short smem[(MODE <= 1) ? 128 * 132 : 128 * 64];
    short* Asm = smem;
    short* Bsm = smem + 128 * 32;

    const int tid = threadIdx.x;
    const int w = tid >> 6, lane = tid & 63, quad = lane >> 4, l15 = lane & 15;
    const int wr = w & 1, wc = w >> 1;
    const int m0 = blockIdx.y * 128, n0 = blockIdx.x * 128;

    const int srow = lane >> 2, slot = lane & 3;
    const int kslot = (slot ^ ((srow >> 1) & 3)) * 8;
    const short* Ag0 = A + (size_t)(m0 + w * 32 + srow) * 1024 + kslot;
    const short* Ag1 = Ag0 + (size_t)16 * 1024;
    const short* Bg0 = Bt + (size_t)(n0 + w * 32 + srow) * 1024 + kslot;
    const short* Bg1 = Bg0 + (size_t)16 * 1024;
    short* Al = Asm + w * 32 * 32;
    short* Bl = Bsm + w * 32 * 32;

    f32x4 acc[4][4];
    #pragma unroll
    for (int r = 0; r < 4; r++)
        #pragma unroll
        for (int c = 0; c < 4; c++) acc[r][c] = f32x4{0.f, 0.f, 0.f, 0.f};

    const int rsw = (l15 >> 1) & 3;
    for (int k0 = 0; k0 < 1024; k0 += 32) {
        __syncthreads();
        gload16(Al,           Ag0 + k0);
        gload16(Al + 16 * 32, Ag1 + k0);
        gload16(Bl,           Bg0 + k0);
        gload16(Bl + 16 * 32, Bg1 + k0);
        __syncthreads();
        bf16x8 af[4], bfr[4];
        #pragma unroll
        for (int rt = 0; rt < 4; rt++)
            af[rt] = *(const bf16x8*)(Asm + (wr * 64 + rt * 16 + l15) * 32 + ((quad ^ rsw) * 8));
        #pragma unroll
        for (int ct = 0; ct < 4; ct++)
            bfr[ct] = *(const bf16x8*)(Bsm + (wc * 64 + ct * 16 + l15) * 32 + ((quad ^ rsw) * 8));
        #pragma unroll
        for (int rt = 0; rt < 4; rt++)
            #pragma unroll
            for (int ct = 0; ct < 4; ct++)
                acc[rt][ct] = mfma16(af[rt], bfr[ct], acc[rt][ct]);
    }

    if constexpr (MODE == 0 || MODE == 1) {
        #pragma unroll
        for (int rt = 0; rt < 4; rt++) {
            #pragma unroll
            for (int i = 0; i < 4; i++) {
                float s = acc[rt][0][i] + acc[rt][1][i] + acc[rt][2][i] + acc[rt][3][i];
                float q = acc[rt][0][i] * acc[rt][0][i] + acc[rt][1][i] * acc[rt][1][i] +
                          acc[rt][2][i] * acc[rt][2][i] + acc[rt][3][i] * acc[rt][3][i];
                #pragma unroll
                for (int off = 1; off < 16; off <<= 1) {
                    s += __shfl_xor(s, off, 64);
                    q += __shfl_xor(q, off, 64);
                }
                float mu = s * (1.f / 64.f);
                float var = q * (1.f / 64.f) - mu * mu;
                float rs = rsqrtf(var + 1e-5f);
                float vals[4];
                #pragma unroll
                for (int ct = 0; ct < 4; ct++) {
                    int hd = ct * 16 + l15;
                    vals[ct] = (acc[rt][ct][i] - mu) * rs * ln_scale[hd] + ln_bias[hd];
                }
                if constexpr (MODE == 0) {
                    int sp = (m0 + wr * 64 + rt * 16 + quad * 4 + i) & 2047;
                    #pragma unroll
                    for (int ct = 0; ct < 2; ct++) {
                        int hd1 = ct * 16 + l15;
                        float ang = (float)sp * exp2f((float)hd1 * (-13.287712379549449f / 32.f));
                        float sn, cs;
                        sincosf(ang, &sn, &cs);
                        float v1 = vals[ct], v2 = vals[ct + 2];
                        vals[ct]     = v1 * cs - v2 * sn;
                        vals[ct + 2] = v1 * sn + v2 * cs;
                    }
                }
                #pragma unroll
                for (int ct = 0; ct < 4; ct++) acc[rt][ct][i] = vals[ct];
            }
        }
        __syncthreads();
        short* Csm = smem;
        #pragma unroll
        for (int rt = 0; rt < 4; rt++)
            #pragma unroll
            for (int ct = 0; ct < 4; ct++)
                #pragma unroll
                for (int i = 0; i < 4; i++)
                    Csm[(wr * 64 + rt * 16 + quad * 4 + i) * 132 + wc * 64 + ct * 16 + l15] =
                        f2s(acc[rt][ct][i]);
        __syncthreads();
        #pragma unroll
        for (int it = 0; it < 8; it++) {
            int row = it * 16 + (tid >> 4);
            int chunk = tid & 15;
            bf16x8 v = *(const bf16x8*)(Csm + row * 132 + chunk * 8);
            int hh = (n0 >> 6) + (chunk >> 3);
            int m = m0 + row, b = m >> 11, sp = m & 2047;
            *(bf16x8*)(outB + ((size_t)(b * 16 + hh) * 2048 + sp) * 64 + (chunk & 7) * 8) = v;
        }
    } else if constexpr (MODE == 2) {
        const int b = m0 >> 11, h = (n0 >> 6) + wc;
        const int sp = (m0 & 2047) + wr * 64 + quad * 4;
        #pragma unroll
        for (int rt = 0; rt < 4; rt++)
            #pragma unroll
            for (int ct = 0; ct < 4; ct++) {
                short4 pk;
                pk.x = f2s(acc[rt][ct][0]); pk.y = f2s(acc[rt][ct][1]);
                pk.z = f2s(acc[rt][ct][2]); pk.w = f2s(acc[rt][ct][3]);
                int hd = ct * 16 + l15;
                *(short4*)(outB + ((size_t)(b * 16 + h) * 64 + hd) * 2048 + sp + rt * 16) = pk;
            }
    } else {
        #pragma unroll
        for (int rt = 0; rt < 4; rt++)
            #pragma unroll
            for (int i = 0; i < 4; i++) {
                size_t m = m0 + wr * 64 + rt * 16 + quad * 4 + i;
                #pragma unroll
                for (int ct = 0; ct < 4; ct++) {
                    int n = n0 + wc * 64 + ct * 16 + l15;
                    outF[m * 1024 + n] = acc[rt][ct][i] + bias_vec[n];
                }
            }
    }
}

// ---------------- attention R4: m97-shaped, LDS-staged K/V, 4-wave blocks ----------------
// S^T = K.Q^T; fixed-max softmax p = exp2(s*0.125*log2e - 8*log2e) (|s|<=8 by LN, RoPE
// norm-preserving); denominator sums the TRUNCATED bf16 p's -> exact softmax of p~.
// LDS: K 2buf x 2planes x (64x32) | V same | P 4 x (32x72).  51.2KB -> 3 blocks/CU.
__global__ __launch_bounds__(256, 3) void attn_kernel(
    const short* __restrict__ Q,   // [64][2048][64]
    const short* __restrict__ K,   // [64][2048][64]
    const short* __restrict__ V,   // [64][64][2048]  (V^T)
    short* __restrict__ AO) {      // [8192][1024] bf16
    __shared__ short smem[8192 + 8192 + 4 * 32 * 72];
    const int tid = threadIdx.x;
    const int w = tid >> 6, lane = tid & 63, quad = lane >> 4, l15 = lane & 15;
    const int bh = blockIdx.x, qt = blockIdx.y;  // grid (64,16): head -> XCD = bh%8
    const short* Qb = Q + (size_t)bh * 2048 * 64;
    const short* Kb = K + (size_t)bh * 2048 * 64;
    const short* Vb = V + (size_t)bh * 64 * 2048;
    short* Pw = smem + 16384 + w * 32 * 72;
    const int q0 = qt * 128 + w * 32;

    // staging: wave w covers rows [16w,16w+16) of each 64-row tile; XOR chunk swizzle
    const int srow = lane >> 2, slot = lane & 3;
    const int sw = (slot ^ ((srow >> 1) & 3)) * 8;
    const short* Kg = Kb + (size_t)(w * 16 + srow) * 64 + sw;     // + sc*64 + ks*32
    const short* Vg = Vb + (size_t)(w * 16 + srow) * 2048 + sw;   // + sc + kh*32
    short* Kl0 = smem + w * 512;           // + buf*4096 + ks*2048
    short* Vl0 = smem + 8192 + w * 512;    // + buf*4096 + kh*2048

    bf16x8 bq[2][2];  // Q as B-operand: B[n=qrow][k=hd]
    #pragma unroll
    for (int nt = 0; nt < 2; nt++)
        #pragma unroll
        for (int ks = 0; ks < 2; ks++)
            bq[nt][ks] = *(const bf16x8*)(Qb + (size_t)(q0 + nt * 16 + l15) * 64 + ks * 32 + quad * 8);

    f32x4 acco[4][2];  // O^T: [ct(hd)][nt(qrow)]
    #pragma unroll
    for (int ct = 0; ct < 4; ct++)
        #pragma unroll
        for (int nt = 0; nt < 2; nt++) acco[ct][nt] = f32x4{0.f, 0.f, 0.f, 0.f};
    float lsum[2] = {0.f, 0.f};
    const int rsw = (l15 >> 1) & 3;
    const int rch = (quad ^ rsw) * 8;

    // preload tile 0 into buffer 0
    gload16(Kl0,        Kg);
    gload16(Kl0 + 2048, Kg + 32);
    gload16(Vl0,        Vg);
    gload16(Vl0 + 2048, Vg + 32);
    __syncthreads();

    #pragma unroll 1
    for (int t = 0; t < 32; t++) {
        const int cur = (t & 1) * 4096;
        if (t < 31) {
            const int nxt = 4096 - cur;
            const int sc = (t + 1) * 64;
            gload16(Kl0 + nxt,        Kg + sc * 64);
            gload16(Kl0 + nxt + 2048, Kg + sc * 64 + 32);
            gload16(Vl0 + nxt,        Vg + sc);
            gload16(Vl0 + nxt + 2048, Vg + sc + 32);
        }
        bf16x8 ak[4][2], av[4][2];
        #pragma unroll
        for (int mt = 0; mt < 4; mt++)
            #pragma unroll
            for (int ks = 0; ks < 2; ks++)
                ak[mt][ks] = *(const bf16x8*)(smem + cur + ks * 2048 + (mt * 16 + l15) * 32 + rch);
        #pragma unroll
        for (int ct = 0; ct < 4; ct++)
            #pragma unroll
            for (int ks = 0; ks < 2; ks++)
                av[ct][ks] = *(const bf16x8*)(smem + 8192 + cur + ks * 2048 + (ct * 16 + l15) * 32 + rch);

        // QK^T -> softmax -> P (bf16-truncate via v_perm; lsum over truncated values)
        #pragma unroll
        for (int mt = 0; mt < 4; mt++) {
            #pragma unroll
            for (int nt = 0; nt < 2; nt++) {
                f32x4 st = f32x4{0.f, 0.f, 0.f, 0.f};
                st = mfma16(ak[mt][0], bq[nt][0], st);
                st = mfma16(ak[mt][1], bq[nt][1], st);
                float e0 = __builtin_amdgcn_exp2f(st[0] * 0.1803368801f - 11.5415605f);
                float e1 = __builtin_amdgcn_exp2f(st[1] * 0.1803368801f - 11.5415605f);
                float e2 = __builtin_amdgcn_exp2f(st[2] * 0.1803368801f - 11.5415605f);
                float e3 = __builtin_amdgcn_exp2f(st[3] * 0.1803368801f - 11.5415605f);
                unsigned int p01 = __builtin_amdgcn_perm(fbits(e1), fbits(e0), 0x07060302u);
                unsigned int p23 = __builtin_amdgcn_perm(fbits(e3), fbits(e2), 0x07060302u);
                lsum[nt] += (bitsf(p01 << 16) + bitsf(p01 & 0xFFFF0000u)) +
                            (bitsf(p23 << 16) + bitsf(p23 & 0xFFFF0000u));
                uint2 pw;
                pw.x = p01; pw.y = p23;
                *(uint2*)(Pw + (nt * 16 + l15) * 72 + mt * 16 + quad * 4) = pw;
            }
        }
        // P^T readback as B-operand (wave-private region, no barrier needed)
        bf16x8 bp[2][2];
        #pragma unroll
        for (int nt = 0; nt < 2; nt++)
            #pragma unroll
            for (int ks = 0; ks < 2; ks++)
                bp[nt][ks] = *(const bf16x8*)(Pw + (nt * 16 + l15) * 72 + ks * 32 + quad * 8);
        #pragma unroll
        for (int ct = 0; ct < 4; ct++)
            #pragma unroll
            for (int nt = 0; nt < 2; nt++)
                #pragma unroll
                for (int ks = 0; ks < 2; ks++)
                    acco[ct][nt] = mfma16(av[ct][ks], bp[nt][ks], acco[ct][nt]);
        __syncthreads();  // waves drain own gloads (vmcnt) then barrier -> nxt buffer ready
    }

    #pragma unroll
    for (int nt = 0; nt < 2; nt++) {
        lsum[nt] += __shfl_xor(lsum[nt], 16, 64);
        lsum[nt] += __shfl_xor(lsum[nt], 32, 64);
    }
    const int b = bh >> 4, h = bh & 15;
    #pragma unroll
    for (int nt = 0; nt < 2; nt++) {
        float inv = 1.f / lsum[nt];
        int sq = q0 + nt * 16 + l15;
        #pragma unroll
        for (int ct = 0; ct < 4; ct++) {
            short4 pk;
            pk.x = f2s(acco[ct][nt][0] * inv); pk.y = f2s(acco[ct][nt][1] * inv);
            pk.z = f2s(acco[ct][nt][2] * inv); pk.w = f2s(acco[ct][nt][3] * inv);
            *(short4*)(AO + ((size_t)b * 2048 + sq) * 1024 + h * 64 + ct * 16 + quad * 4) = pk;
        }
    }
}

extern "C" void kernel_launch(void* const* d_in, const int* in_sizes, int n_in,
                              void* d_out, int out_size, void* d_ws, size_t ws_size,
                              hipStream_t stream) {
    (void)in_sizes; (void)n_in; (void)out_size; (void)ws_size;
    const float* x      = (const float*)d_in[0];
    const float* ctx    = (const float*)d_in[1];
    const float* q_w    = (const float*)d_in[2];
    const float* kv_w   = (const float*)d_in[3];
    const float* qn_s   = (const float*)d_in[4];
    const float* qn_b   = (const float*)d_in[5];
    const float* kn_s   = (const float*)d_in[6];
    const float* kn_b   = (const float*)d_in[7];
    const float* proj_w = (const float*)d_in[8];
    const float* proj_b = (const float*)d_in[9];
    float* out = (float*)d_out;

    char* ws = (char*)d_ws;
    const size_t MB = 1024 * 1024;
    short* xb  = (short*)(ws + 0 * MB);
    short* cb  = (short*)(ws + 16 * MB);
    short* Qb  = (short*)(ws + 32 * MB);   // [64][2048][64] post LN+RoPE
    short* Kb  = (short*)(ws + 48 * MB);   // [64][2048][64] post LN
    short* Vt  = (short*)(ws + 64 * MB);   // [64][64][2048]
    short* AO  = (short*)(ws + 80 * MB);   // [8192][1024]
    short* WqT = (short*)(ws + 96 * MB);
    short* WkT = (short*)(ws + 98 * MB);
    short* WvT = (short*)(ws + 100 * MB);
    short* WpT = (short*)(ws + 102 * MB);

    conv_to_bf16<<<16384, 256, 0, stream>>>(x, ctx, xb, cb);
    transpose_weights<<<dim3(32, 32, 4), 256, 0, stream>>>(q_w, kv_w, proj_w, WqT, WkT, WvT, WpT);
    gemm128<0><<<dim3(8, 64), 256, 0, stream>>>(xb, WqT, qn_s, qn_b, Qb, nullptr, nullptr);
    gemm128<1><<<dim3(8, 64), 256, 0, stream>>>(cb, WkT, kn_s, kn_b, Kb, nullptr, nullptr);
    gemm128<2><<<dim3(8, 64), 256, 0, stream>>>(cb, WvT, nullptr, nullptr, Vt, nullptr, nullptr);
    attn_kernel<<<dim3(64, 16), 256, 0, stream>>>(Qb, Kb, Vt, AO);
    gemm128<3><<<dim3(8, 64), 256, 0, stream>>>(AO, WpT, nullptr, nullptr, nullptr, out, proj_b);
}

// Round 7
// 348.189 us; speedup vs baseline: 1.4760x; 1.0832x over previous
//
#include <hip/hip_runtime.h>
#include <hip/hip_bf16.h>

// CrossAttention R6 = R5 + staging-offset fix. R5's NaN: gemm128 per-wave LDS base was
// w*512 (copied from attn where waves stage 16 rows), but GEMM waves stage 32 rows
// (1024 shorts) -> waves overlapped and tile rows 40..127 were never written
// (uninitialized LDS -> NaN through MFMA). Correct: Al/Bl at w*1024, 2nd gload +512.
//  - gemm128: double-buffered K-loop (preload + prefetch-next + ONE barrier/iter).
//  - K-proj and V-proj merged into one N=2048 GEMM over contiguous WkvT.
//  - attn: R4 structure (102us, MfmaUtil 29%), denominator sums untruncated exp2.

typedef short bf16x8 __attribute__((ext_vector_type(8)));
typedef float f32x4 __attribute__((ext_vector_type(4)));

__device__ __forceinline__ short f2s(float f) {
    __hip_bfloat16 h = __float2bfloat16(f);
    return __builtin_bit_cast(short, h);
}

__device__ __forceinline__ f32x4 mfma16(bf16x8 a, bf16x8 b, f32x4 c) {
    return __builtin_amdgcn_mfma_f32_16x16x32_bf16(a, b, c, 0, 0, 0);
}

__device__ __forceinline__ void gload16(short* lds, const short* g) {
    __builtin_amdgcn_global_load_lds((const __attribute__((address_space(1))) void*)g,
                                     (__attribute__((address_space(3))) void*)lds,
                                     16, 0, 0);
}

__device__ __forceinline__ unsigned int fbits(float f) {
    return __builtin_bit_cast(unsigned int, f);
}

// ---------------- prep: fp32 -> bf16 for activations ----------------
__global__ __launch_bounds__(256) void conv_to_bf16(const float* __restrict__ x,
                                                    const float* __restrict__ ctx,
                                                    short* __restrict__ xb,
                                                    short* __restrict__ cb) {
    const size_t NV = 2097152;
    size_t i = (size_t)blockIdx.x * 256 + threadIdx.x;
    const float4* src = (i < NV) ? (const float4*)x : (const float4*)ctx;
    short* dst = (i < NV) ? xb : cb;
    size_t idx = (i < NV) ? i : i - NV;
    float4 v = src[idx];
    short4 o;
    o.x = f2s(v.x); o.y = f2s(v.y); o.z = f2s(v.z); o.w = f2s(v.w);
    ((short4*)dst)[idx] = o;
}

// ---------------- prep: W -> W^T bf16 (K+V halves contiguous in WkvT) ----------------
__global__ __launch_bounds__(256) void transpose_weights(
    const float* __restrict__ q_w, const float* __restrict__ kv_w,
    const float* __restrict__ proj_w,
    short* __restrict__ WqT, short* __restrict__ WkvT, short* __restrict__ WpT) {
    __shared__ float t[32][33];
    const float* src; short* dst; int ld, coff;
    switch (blockIdx.z) {
        case 0:  src = q_w;    dst = WqT;                 ld = 1024; coff = 0;    break;
        case 1:  src = kv_w;   dst = WkvT;                ld = 2048; coff = 0;    break;
        case 2:  src = kv_w;   dst = WkvT + 1024 * 1024;  ld = 2048; coff = 1024; break;
        default: src = proj_w; dst = WpT;                 ld = 1024; coff = 0;    break;
    }
    int n0 = blockIdx.x * 32, k0 = blockIdx.y * 32;
    int tx = threadIdx.x & 31, ty = threadIdx.x >> 5;
    #pragma unroll
    for (int j = 0; j < 32; j += 8)
        t[ty + j][tx] = src[(size_t)(k0 + ty + j) * ld + coff + n0 + tx];
    __syncthreads();
    #pragma unroll
    for (int j = 0; j < 32; j += 8)
        dst[(size_t)(n0 + ty + j) * 1024 + k0 + tx] = f2s(t[tx][ty + j]);
}

// ---------------- GEMM 128x128, K=1024, double-buffered staging ----------------
// MODE 0: Q proj -> per-head LN -> RoPE -> Q[b,h,s,64] bf16 (coalesced via LDS overlay)
// MODE 1: KV proj (N=2048): n0<1024 -> K path (LN -> K[b,h,sc,64]); else V path
//         (V^T[b,h,64,sc] transposed b64 stores)
// MODE 2: out proj -> + bias -> fp32 out
template <int MODE>
__global__ __launch_bounds__(256) void gemm128(
    const short* __restrict__ A,    // [8192][1024] bf16 row-major
    const short* __restrict__ Bt,   // [N][1024] bf16 (N-major, K contiguous)
    const float* __restrict__ ln_scale,
    const float* __restrict__ ln_bias,
    short* __restrict__ outB,
    short* __restrict__ outB2,
    float* __restrict__ outF,
    const float* __restrict__ bias_vec) {
    // staging: 2 bufs x (A 128x32 + B 128x32) = 16384 shorts; epilogue overlay 128x132.
    __shared__ short smem[(MODE <= 1) ? 16896 : 16384];
    const int tid = threadIdx.x;
    const int w = tid >> 6, lane = tid & 63, quad = lane >> 4, l15 = lane & 15;
    const int wr = w & 1, wc = w >> 1;
    const int m0 = blockIdx.y * 128, n0 = blockIdx.x * 128;

    const int srow = lane >> 2, slot = lane & 3;
    const int kslot = (slot ^ ((srow >> 1) & 3)) * 8;  // XOR swizzle: 2-way banks on read
    const short* Ag0 = A + (size_t)(m0 + w * 32 + srow) * 1024 + kslot;
    const short* Ag1 = Ag0 + (size_t)16 * 1024;
    const short* Bg0 = Bt + (size_t)(n0 + w * 32 + srow) * 1024 + kslot;
    const short* Bg1 = Bg0 + (size_t)16 * 1024;
    // wave w stages rows [w*32, w*32+32): 1024 shorts per tile (two 512-short gloads)
    short* Al = smem + w * 1024;           // + buf*8192
    short* Bl = smem + 4096 + w * 1024;    // + buf*8192

    f32x4 acc[4][4];
    #pragma unroll
    for (int r = 0; r < 4; r++)
        #pragma unroll
        for (int c = 0; c < 4; c++) acc[r][c] = f32x4{0.f, 0.f, 0.f, 0.f};

    const int rsw = (l15 >> 1) & 3;
    const int rch = (quad ^ rsw) * 8;

    // preload k-tile 0 into buffer 0
    gload16(Al,       Ag0);
    gload16(Al + 512, Ag1);
    gload16(Bl,       Bg0);
    gload16(Bl + 512, Bg1);
    __syncthreads();

    #pragma unroll 1
    for (int t = 0; t < 32; t++) {
        const int cur = (t & 1) * 8192;
        if (t < 31) {
            const int nxt = 8192 - cur;
            const int k0 = (t + 1) * 32;
            gload16(Al + nxt,       Ag0 + k0);
            gload16(Al + nxt + 512, Ag1 + k0);
            gload16(Bl + nxt,       Bg0 + k0);
            gload16(Bl + nxt + 512, Bg1 + k0);
        }
        bf16x8 af[4], bfr[4];
        #pragma unroll
        for (int rt = 0; rt < 4; rt++)
            af[rt] = *(const bf16x8*)(smem + cur + (wr * 64 + rt * 16 + l15) * 32 + rch);
        #pragma unroll
        for (int ct = 0; ct < 4; ct++)
            bfr[ct] = *(const bf16x8*)(smem + cur + 4096 + (wc * 64 + ct * 16 + l15) * 32 + rch);
        #pragma unroll
        for (int rt = 0; rt < 4; rt++)
            #pragma unroll
            for (int ct = 0; ct < 4; ct++)
                acc[rt][ct] = mfma16(af[rt], bfr[ct], acc[rt][ct]);
        __syncthreads();  // drains this iter's prefetch (covered by compute) + LDS reads
    }

    // epilogue: lane holds C[row = wr*64+rt*16+quad*4+i][col = wc*64+ct*16+l15]
    const bool vpath = (MODE == 1) && (n0 >= 1024);
    if constexpr (MODE == 0 || MODE == 1) {
        if (!vpath) {
            #pragma unroll
            for (int rt = 0; rt < 4; rt++) {
                #pragma unroll
                for (int i = 0; i < 4; i++) {
                    float s = acc[rt][0][i] + acc[rt][1][i] + acc[rt][2][i] + acc[rt][3][i];
                    float q = acc[rt][0][i] * acc[rt][0][i] + acc[rt][1][i] * acc[rt][1][i] +
                              acc[rt][2][i] * acc[rt][2][i] + acc[rt][3][i] * acc[rt][3][i];
                    #pragma unroll
                    for (int off = 1; off < 16; off <<= 1) {
                        s += __shfl_xor(s, off, 64);
                        q += __shfl_xor(q, off, 64);
                    }
                    float mu = s * (1.f / 64.f);
                    float var = q * (1.f / 64.f) - mu * mu;
                    float rs = rsqrtf(var + 1e-5f);
                    float vals[4];
                    #pragma unroll
                    for (int ct = 0; ct < 4; ct++) {
                        int hd = ct * 16 + l15;
                        vals[ct] = (acc[rt][ct][i] - mu) * rs * ln_scale[hd] + ln_bias[hd];
                    }
                    if constexpr (MODE == 0) {  // RoPE pairs (hd, hd+32) = (ct, ct+2)
                        int sp = (m0 + wr * 64 + rt * 16 + quad * 4 + i) & 2047;
                        #pragma unroll
                        for (int ct = 0; ct < 2; ct++) {
                            int hd1 = ct * 16 + l15;
                            float ang = (float)sp * exp2f((float)hd1 * (-13.287712379549449f / 32.f));
                            float sn, cs;
                            sincosf(ang, &sn, &cs);
                            float v1 = vals[ct], v2 = vals[ct + 2];
                            vals[ct]     = v1 * cs - v2 * sn;
                            vals[ct + 2] = v1 * sn + v2 * cs;
                        }
                    }
                    #pragma unroll
                    for (int ct = 0; ct < 4; ct++) acc[rt][ct][i] = vals[ct];
                }
            }
            __syncthreads();
            short* Csm = smem;  // overlay: [128][132] bf16, +4 pad
            #pragma unroll
            for (int rt = 0; rt < 4; rt++)
                #pragma unroll
                for (int ct = 0; ct < 4; ct++)
                    #pragma unroll
                    for (int i = 0; i < 4; i++)
                        Csm[(wr * 64 + rt * 16 + quad * 4 + i) * 132 + wc * 64 + ct * 16 + l15] =
                            f2s(acc[rt][ct][i]);
            __syncthreads();
            #pragma unroll
            for (int it = 0; it < 8; it++) {
                int row = it * 16 + (tid >> 4);
                int chunk = tid & 15;
                bf16x8 v = *(const bf16x8*)(Csm + row * 132 + chunk * 8);
                int hh = ((n0 & 1023) >> 6) + (chunk >> 3);
                int m = m0 + row, b = m >> 11, sp = m & 2047;
                *(bf16x8*)(outB + ((size_t)(b * 16 + hh) * 2048 + sp) * 64 + (chunk & 7) * 8) = v;
            }
        } else {
            // V path: transposed store V^T[b,h,hd,sc]
            const int b = m0 >> 11, h = ((n0 - 1024) >> 6) + wc;
            const int sp = (m0 & 2047) + wr * 64 + quad * 4;
            #pragma unroll
            for (int rt = 0; rt < 4; rt++)
                #pragma unroll
                for (int ct = 0; ct < 4; ct++) {
                    short4 pk;
                    pk.x = f2s(acc[rt][ct][0]); pk.y = f2s(acc[rt][ct][1]);
                    pk.z = f2s(acc[rt][ct][2]); pk.w = f2s(acc[rt][ct][3]);
                    int hd = ct * 16 + l15;
                    *(short4*)(outB2 + ((size_t)(b * 16 + h) * 64 + hd) * 2048 + sp + rt * 16) = pk;
                }
        }
    } else {
        #pragma unroll
        for (int rt = 0; rt < 4; rt++)
            #pragma unroll
            for (int i = 0; i < 4; i++) {
                size_t m = m0 + wr * 64 + rt * 16 + quad * 4 + i;
                #pragma unroll
                for (int ct = 0; ct < 4; ct++) {
                    int n = n0 + wc * 64 + ct * 16 + l15;
                    outF[m * 1024 + n] = acc[rt][ct][i] + bias_vec[n];
                }
            }
    }
}

// ---------------- attention (R4 structure): m97-shaped, LDS-staged K/V ----------------
// S^T = K.Q^T; fixed-max softmax p = exp2(s*0.125*log2e - 8*log2e) (|s|<=8 by LN, RoPE
// norm-preserving). LDS: K 2buf | V 2buf | P 4x(32x72). 50KB.
__global__ __launch_bounds__(256, 3) void attn_kernel(
    const short* __restrict__ Q,   // [64][2048][64]
    const short* __restrict__ K,   // [64][2048][64]
    const short* __restrict__ V,   // [64][64][2048]  (V^T)
    short* __restrict__ AO) {      // [8192][1024] bf16
    __shared__ short smem[8192 + 8192 + 4 * 32 * 72];
    const int tid = threadIdx.x;
    const int w = tid >> 6, lane = tid & 63, quad = lane >> 4, l15 = lane & 15;
    const int bh = blockIdx.x, qt = blockIdx.y;  // grid (64,16): head -> XCD = bh%8
    const short* Qb = Q + (size_t)bh * 2048 * 64;
    const short* Kb = K + (size_t)bh * 2048 * 64;
    const short* Vb = V + (size_t)bh * 64 * 2048;
    short* Pw = smem + 16384 + w * 32 * 72;
    const int q0 = qt * 128 + w * 32;

    const int srow = lane >> 2, slot = lane & 3;
    const int sw = (slot ^ ((srow >> 1) & 3)) * 8;
    const short* Kg = Kb + (size_t)(w * 16 + srow) * 64 + sw;
    const short* Vg = Vb + (size_t)(w * 16 + srow) * 2048 + sw;
    short* Kl0 = smem + w * 512;           // 16 rows/wave/plane
    short* Vl0 = smem + 8192 + w * 512;

    bf16x8 bq[2][2];  // Q as B-operand: B[n=qrow][k=hd]
    #pragma unroll
    for (int nt = 0; nt < 2; nt++)
        #pragma unroll
        for (int ks = 0; ks < 2; ks++)
            bq[nt][ks] = *(const bf16x8*)(Qb + (size_t)(q0 + nt * 16 + l15) * 64 + ks * 32 + quad * 8);

    f32x4 acco[4][2];  // O^T: [ct(hd)][nt(qrow)]
    #pragma unroll
    for (int ct = 0; ct < 4; ct++)
        #pragma unroll
        for (int nt = 0; nt < 2; nt++) acco[ct][nt] = f32x4{0.f, 0.f, 0.f, 0.f};
    float lsum[2] = {0.f, 0.f};
    const int rsw = (l15 >> 1) & 3;
    const int rch = (quad ^ rsw) * 8;

    gload16(Kl0,        Kg);
    gload16(Kl0 + 2048, Kg + 32);
    gload16(Vl0,        Vg);
    gload16(Vl0 + 2048, Vg + 32);
    __syncthreads();

    #pragma unroll 1
    for (int t = 0; t < 32; t++) {
        const int cur = (t & 1) * 4096;
        if (t < 31) {
            const int nxt = 4096 - cur;
            const int sc = (t + 1) * 64;
            gload16(Kl0 + nxt,        Kg + sc * 64);
            gload16(Kl0 + nxt + 2048, Kg + sc * 64 + 32);
            gload16(Vl0 + nxt,        Vg + sc);
            gload16(Vl0 + nxt + 2048, Vg + sc + 32);
        }
        bf16x8 ak[4][2], av[4][2];
        #pragma unroll
        for (int mt = 0; mt < 4; mt++)
            #pragma unroll
            for (int ks = 0; ks < 2; ks++)
                ak[mt][ks] = *(const bf16x8*)(smem + cur + ks * 2048 + (mt * 16 + l15) * 32 + rch);
        #pragma unroll
        for (int ct = 0; ct < 4; ct++)
            #pragma unroll
            for (int ks = 0; ks < 2; ks++)
                av[ct][ks] = *(const bf16x8*)(smem + 8192 + cur + ks * 2048 + (ct * 16 + l15) * 32 + rch);

        #pragma unroll
        for (int mt = 0; mt < 4; mt++) {
            #pragma unroll
            for (int nt = 0; nt < 2; nt++) {
                f32x4 st = f32x4{0.f, 0.f, 0.f, 0.f};
                st = mfma16(ak[mt][0], bq[nt][0], st);
                st = mfma16(ak[mt][1], bq[nt][1], st);
                float e0 = __builtin_amdgcn_exp2f(st[0] * 0.1803368801f - 11.5415605f);
                float e1 = __builtin_amdgcn_exp2f(st[1] * 0.1803368801f - 11.5415605f);
                float e2 = __builtin_amdgcn_exp2f(st[2] * 0.1803368801f - 11.5415605f);
                float e3 = __builtin_amdgcn_exp2f(st[3] * 0.1803368801f - 11.5415605f);
                lsum[nt] += (e0 + e1) + (e2 + e3);
                unsigned int p01 = __builtin_amdgcn_perm(fbits(e1), fbits(e0), 0x07060302u);
                unsigned int p23 = __builtin_amdgcn_perm(fbits(e3), fbits(e2), 0x07060302u);
                uint2 pw;
                pw.x = p01; pw.y = p23;
                *(uint2*)(Pw + (nt * 16 + l15) * 72 + mt * 16 + quad * 4) = pw;
            }
        }
        bf16x8 bp[2][2];
        #pragma unroll
        for (int nt = 0; nt < 2; nt++)
            #pragma unroll
            for (int ks = 0; ks < 2; ks++)
                bp[nt][ks] = *(const bf16x8*)(Pw + (nt * 16 + l15) * 72 + ks * 32 + quad * 8);
        #pragma unroll
        for (int ct = 0; ct < 4; ct++)
            #pragma unroll
            for (int nt = 0; nt < 2; nt++)
                #pragma unroll
                for (int ks = 0; ks < 2; ks++)
                    acco[ct][nt] = mfma16(av[ct][ks], bp[nt][ks], acco[ct][nt]);
        __syncthreads();
    }

    #pragma unroll
    for (int nt = 0; nt < 2; nt++) {
        lsum[nt] += __shfl_xor(lsum[nt], 16, 64);
        lsum[nt] += __shfl_xor(lsum[nt], 32, 64);
    }
    const int b = bh >> 4, h = bh & 15;
    #pragma unroll
    for (int nt = 0; nt < 2; nt++) {
        float inv = 1.f / lsum[nt];
        int sq = q0 + nt * 16 + l15;
        #pragma unroll
        for (int ct = 0; ct < 4; ct++) {
            short4 pk;
            pk.x = f2s(acco[ct][nt][0] * inv); pk.y = f2s(acco[ct][nt][1] * inv);
            pk.z = f2s(acco[ct][nt][2] * inv); pk.w = f2s(acco[ct][nt][3] * inv);
            *(short4*)(AO + ((size_t)b * 2048 + sq) * 1024 + h * 64 + ct * 16 + quad * 4) = pk;
        }
    }
}

extern "C" void kernel_launch(void* const* d_in, const int* in_sizes, int n_in,
                              void* d_out, int out_size, void* d_ws, size_t ws_size,
                              hipStream_t stream) {
    (void)in_sizes; (void)n_in; (void)out_size; (void)ws_size;
    const float* x      = (const float*)d_in[0];
    const float* ctx    = (const float*)d_in[1];
    const float* q_w    = (const float*)d_in[2];
    const float* kv_w   = (const float*)d_in[3];
    const float* qn_s   = (const float*)d_in[4];
    const float* qn_b   = (const float*)d_in[5];
    const float* kn_s   = (const float*)d_in[6];
    const float* kn_b   = (const float*)d_in[7];
    const float* proj_w = (const float*)d_in[8];
    const float* proj_b = (const float*)d_in[9];
    float* out = (float*)d_out;

    char* ws = (char*)d_ws;
    const size_t MB = 1024 * 1024;
    short* xb   = (short*)(ws + 0 * MB);
    short* cb   = (short*)(ws + 16 * MB);
    short* Qb   = (short*)(ws + 32 * MB);   // [64][2048][64] post LN+RoPE
    short* Kb   = (short*)(ws + 48 * MB);   // [64][2048][64] post LN
    short* Vt   = (short*)(ws + 64 * MB);   // [64][64][2048]
    short* AO   = (short*)(ws + 80 * MB);   // [8192][1024]
    short* WqT  = (short*)(ws + 96 * MB);   // 2MB
    short* WkvT = (short*)(ws + 98 * MB);   // 4MB  [2048][1024]
    short* WpT  = (short*)(ws + 102 * MB);  // 2MB

    conv_to_bf16<<<16384, 256, 0, stream>>>(x, ctx, xb, cb);
    transpose_weights<<<dim3(32, 32, 4), 256, 0, stream>>>(q_w, kv_w, proj_w, WqT, WkvT, WpT);
    gemm128<0><<<dim3(8, 64), 256, 0, stream>>>(xb, WqT, qn_s, qn_b, Qb, nullptr, nullptr, nullptr);
    gemm128<1><<<dim3(16, 64), 256, 0, stream>>>(cb, WkvT, kn_s, kn_b, Kb, Vt, nullptr, nullptr);
    attn_kernel<<<dim3(64, 16), 256, 0, stream>>>(Qb, Kb, Vt, AO);
    gemm128<2><<<dim3(8, 64), 256, 0, stream>>>(AO, WpT, nullptr, nullptr, nullptr, nullptr, out, proj_b);
}